// Round 4
// baseline (596.886 us; speedup 1.0000x reference)
//
#include <hip/hip_runtime.h>
#include <cmath>

// B,T,D,H = 4096,48,64,128
#define Bb 4096
#define Tt 48
#define Dd 64
#define Hh 128
#define NB 16      // batch rows per block (M of MFMA)
#define NTHR 1024  // 16 waves

typedef unsigned short ushort_t;
typedef __attribute__((ext_vector_type(8))) short short8;    // 8 bf16 = 4 VGPRs (MFMA A/B frag)
typedef __attribute__((ext_vector_type(4))) float floatx4;   // MFMA C/D frag

// ---- workspace layout (floats) ----
#define WS_DEN   0     // denoms[48]
#define WS_LOSS  48
#define WS_FRAGS 64    // bf16 frag area starts here (16B aligned)
// frag indices (each frag = 64 lanes x 8 bf16 = 512 ushorts = 1 KB)
#define FR_F 0         // 256 frags: gates  [cg:8][g:4][ks:8]  K=256 (c_c|m|h)
#define FR_A 256       // 16: W_td_h        [cg:8][ks:2]       K=64
#define FR_B 272       // 16: W_hist        [cd:4][ks:4]       K=128
#define FR_C 288       // 8 : W_feat masked [cd:4][ks:2]       K=64
#define FR_E 296       // 16: W_comb        [cd:4][ks:4]       K=128
#define N_FRAGS 312

__device__ __forceinline__ ushort_t f2bf(float x) {   // RNE float->bf16 bits
  unsigned int u = __float_as_uint(x);
  u += 0x7fffu + ((u >> 16) & 1u);
  return (ushort_t)(u >> 16);
}
__device__ __forceinline__ float sigmoidf_(float x) { return 1.0f / (1.0f + __expf(-x)); }
__device__ __forceinline__ float tanhf_(float x) { return 2.0f / (1.0f + __expf(-2.0f * x)) - 1.0f; }

// ---------------- kernel 0: pack weights into per-lane MFMA B-frags (bf16) ----------------
// B-frag layout for mfma_f32_16x16x32_bf16: lane l holds B[k=(l>>4)*8+j][n=l&15], j=0..7
__global__ void prep_kernel(const float* __restrict__ W_td_h, const float* __restrict__ W_hist,
                            const float* __restrict__ W_feat, const float* __restrict__ W_comb,
                            const float* __restrict__ W_ih, const float* __restrict__ W_hh,
                            float* __restrict__ ws) {
  int f = blockIdx.x;                 // one frag per block
  int tid = threadIdx.x;              // 256 threads, 2 elems each
  if (f == 0 && tid < 64) ws[tid] = 0.0f;   // zero denoms + loss
  ushort_t* fb = (ushort_t*)(ws + WS_FRAGS);
  #pragma unroll
  for (int u = 0; u < 2; u++) {
    int e = tid * 2 + u;              // 0..511 = l*8 + j
    int l = e >> 3, j = e & 7;
    int n16 = l & 15;
    int kq = ((l >> 4) << 3) + j;     // quad*8 + j  (0..31)
    float v;
    if (f < 256) {
      int cg = f >> 5, g = (f >> 3) & 3, ks = f & 7;
      int n = g * 128 + cg * 16 + n16;          // gate row in [512]
      int k = ks * 32 + kq;                     // 0..255: 0-127 -> W_ih, 128-255 -> W_hh
      v = (k < 128) ? W_ih[n * 128 + k] : W_hh[n * 128 + (k - 128)];
    } else if (f < 272) {
      int ff = f - 256, cg = ff >> 1, ks = ff & 1;
      int n = cg * 16 + n16;                    // 0..127
      v = W_td_h[n * 64 + ks * 32 + kq];
    } else if (f < 288) {
      int ff = f - 272, cd = ff >> 2, ks = ff & 3;
      int n = cd * 16 + n16;                    // 0..63
      v = W_hist[n * 128 + ks * 32 + kq];
    } else if (f < 296) {
      int ff = f - 288, cd = ff >> 1, ks = ff & 1;
      int n = cd * 16 + n16;
      int k = ks * 32 + kq;
      v = (n == k) ? 0.0f : W_feat[n * 64 + k];  // zeroed diagonal
    } else {
      int ff = f - 296, cd = ff >> 2, ks = ff & 3;
      int n = cd * 16 + n16;
      v = W_comb[n * 128 + ks * 32 + kq];       // cols: 0-63 gamma_x, 64-127 m
    }
    fb[f * 512 + e] = f2bf(v);
  }
}

// ---------------- kernel 1: denom_t = sum over [B,D] of masks[:,t,:] ----------------
__global__ void denom_kernel(const float* __restrict__ masks, float* __restrict__ ws) {
  int t = blockIdx.x >> 4;
  int chunk = blockIdx.x & 15;
  int base = chunk * 256;
  int tid = threadIdx.x;
  int j = tid & 63;
  int brow = tid >> 6;
  float s = 0.0f;
  for (int i = 0; i < 64; i++) {
    int b = base + i * 4 + brow;
    s += masks[((size_t)b * Tt + t) * Dd + j];
  }
  for (int off = 32; off > 0; off >>= 1) s += __shfl_down(s, off, 64);
  __shared__ float red[4];
  if ((tid & 63) == 0) red[tid >> 6] = s;
  __syncthreads();
  if (tid == 0) atomicAdd(&ws[WS_DEN + t], red[0] + red[1] + red[2] + red[3]);
}

// ---------------- kernel 2: persistent MFMA recurrence, 16 waves ----------------
// Roles: w0-7  = gates i,f (cols cg*16..) + stage A + LSTM state owner + input staging
//        w8-11 = gates g,o + stage B (x_h) for colD group w-8
//        w12-15= gates g,o + stages E (alpha) and C (z_h) + output epilogue
__global__ __launch_bounds__(NTHR, 4)
void main_kernel(const float* __restrict__ values, const float* __restrict__ masks,
                 const float* __restrict__ deltas, const float* __restrict__ W_td_x,
                 const float* __restrict__ b_td_h, const float* __restrict__ b_td_x,
                 const float* __restrict__ b_hist, const float* __restrict__ b_feat,
                 const float* __restrict__ b_comb,
                 const float* __restrict__ b_ih, const float* __restrict__ b_hh,
                 float* ws, float* __restrict__ out) {
  __shared__ __align__(16) ushort_t act[16 * 264];   // bf16 [16][256+8]: c_c | m | h_dec
  __shared__ __align__(16) ushort_t dbuf[16 * 72];   // bf16 d
  __shared__ __align__(16) ushort_t gxbuf[16 * 72];  // bf16 gamma_x
  __shared__ __align__(16) ushort_t xcbuf[16 * 72];  // bf16 x_c
  __shared__ __align__(16) float xmbuf[16 * 132];    // fp32 interleaved [x,m] pairs
  __shared__ __align__(16) float xhbuf[16 * 68];     // fp32 x_h
  __shared__ __align__(16) float pbuf[4096];         // [r:4][cg:8][lane:64] float2 {tanh(g), sig(o)}
  __shared__ float red[16];

  int tid = threadIdx.x;
  int w = tid >> 6;            // wave 0..15
  int lane = tid & 63;
  int l15 = lane & 15;
  int quad = lane >> 4;
  int cg = w & 7;              // gate column group (16 cols of H=128)
  bool lo = (w < 8);
  int b0 = blockIdx.x * NB;
  const ushort_t* fb = (const ushort_t*)(ws + WS_FRAGS);

  // ---- gate weight frags: 2 gates x 8 ks = 16 frags (64 VGPR) ----
  short8 wG[16];
  {
    int gb = lo ? 0 : 2;   // lo: gates i(0),f(1); hi: g(2),o(3)
    #pragma unroll
    for (int lg = 0; lg < 2; lg++)
      #pragma unroll
      for (int ks = 0; ks < 8; ks++)
        wG[lg * 8 + ks] =
            *(const short8*)(fb + (size_t)(FR_F + cg * 32 + (gb + lg) * 8 + ks) * 512 + lane * 8);
  }
  // ---- role weight frags (union, max 6 frags = 24 VGPR) ----
  short8 wX[6];
  if (lo) {
    #pragma unroll
    for (int ks = 0; ks < 2; ks++)
      wX[ks] = *(const short8*)(fb + (size_t)(FR_A + cg * 2 + ks) * 512 + lane * 8);
  } else if (w < 12) {
    #pragma unroll
    for (int ks = 0; ks < 4; ks++)
      wX[ks] = *(const short8*)(fb + (size_t)(FR_B + (w - 8) * 4 + ks) * 512 + lane * 8);
  } else {
    #pragma unroll
    for (int ks = 0; ks < 4; ks++)
      wX[ks] = *(const short8*)(fb + (size_t)(FR_E + (w - 12) * 4 + ks) * 512 + lane * 8);
    #pragma unroll
    for (int ks = 0; ks < 2; ks++)
      wX[4 + ks] = *(const short8*)(fb + (size_t)(FR_C + (w - 12) * 2 + ks) * 512 + lane * 8);
  }

  // ---- biases ----
  int colh = cg * 16 + l15;          // gate/A columns (H=128)
  float biasG0, biasG1;
  if (lo) { biasG0 = b_ih[colh] + b_hh[colh];  biasG1 = b_ih[128 + colh] + b_hh[128 + colh]; }
  else    { biasG0 = b_ih[256 + colh] + b_hh[256 + colh];  biasG1 = b_ih[384 + colh] + b_hh[384 + colh]; }
  int colD = (w & 3) * 16 + l15;     // B/C/E columns (D=64)
  float biasAC = lo ? b_td_h[colh] : b_feat[colD];
  float biasBE = (w < 12) ? b_hist[colD] : b_comb[colD];

  // ---- input staging mapping (lo waves only; 2 consecutive elems/thread) ----
  int e0 = tid * 2;
  int lb = e0 >> 6, li = e0 & 63;
  size_t gbase = 0;
  float diag0 = 0, diag1 = 0, btx0 = 0, btx1 = 0;
  float2 px, pm, pd;
  if (lo) {
    gbase = ((size_t)(b0 + lb) * Tt) * Dd + li;
    diag0 = W_td_x[li * 64 + li];  diag1 = W_td_x[(li + 1) * 64 + (li + 1)];
    btx0 = b_td_x[li];  btx1 = b_td_x[li + 1];
    px = *(const float2*)(values + gbase);
    pm = *(const float2*)(masks + gbase);
    pd = *(const float2*)(deltas + gbase);
  }

  float* impt = out + 1;             // only meaningful for w12-15
  if (w >= 12) impt = out + 1 + (size_t)(b0 + quad * 4) * (Tt * Dd) + colD;

  floatx4 aG0, aG1, accP;            // gate accumulators persist across iters; accP = alpha
  float h_reg[4] = {0.f, 0.f, 0.f, 0.f};
  float c_reg[4] = {0.f, 0.f, 0.f, 0.f};
  float loss_acc = 0.0f;

  for (int t = 0; t < Tt; t++) {
    __syncthreads();                               // B1: prev phase3 cc/pbuf-region reads done
    // ---- phase0: cc-part of PREV step's gates (act cc from prev S3 still valid);
    //      hi waves finish g,o -> pbuf; lo waves stage inputs ----
    if (t > 0) {
      short8 cf0 = *(const short8*)(&act[l15 * 264 + quad * 8]);
      short8 cf1 = *(const short8*)(&act[l15 * 264 + 32 + quad * 8]);
      aG0 = __builtin_amdgcn_mfma_f32_16x16x32_bf16(cf0, wG[0], aG0, 0, 0, 0);
      aG0 = __builtin_amdgcn_mfma_f32_16x16x32_bf16(cf1, wG[1], aG0, 0, 0, 0);
      aG1 = __builtin_amdgcn_mfma_f32_16x16x32_bf16(cf0, wG[8], aG1, 0, 0, 0);
      aG1 = __builtin_amdgcn_mfma_f32_16x16x32_bf16(cf1, wG[9], aG1, 0, 0, 0);
      if (!lo) {
        #pragma unroll
        for (int r = 0; r < 4; r++) {
          float tg = tanhf_(aG0[r]);               // tanh(g)
          float so = sigmoidf_(aG1[r]);            // sigmoid(o)
          *(float2*)(&pbuf[((r * 8 + cg) * 64 + lane) * 2]) = make_float2(tg, so);
        }
      }
    }
    if (lo) {                                      // stage x,m,d, gamma_x
      *(float4*)(&xmbuf[lb * 132 + 2 * li]) = make_float4(px.x, pm.x, px.y, pm.y);
      *(unsigned int*)(&act[lb * 264 + 64 + li]) =
          (unsigned int)f2bf(pm.x) | ((unsigned int)f2bf(pm.y) << 16);
      *(unsigned int*)(&dbuf[lb * 72 + li]) =
          (unsigned int)f2bf(pd.x) | ((unsigned int)f2bf(pd.y) << 16);
      float g0 = __expf(-fmaxf(pd.x * diag0 + btx0, 0.0f));
      float g1 = __expf(-fmaxf(pd.y * diag1 + btx1, 0.0f));
      *(unsigned int*)(&gxbuf[lb * 72 + li]) =
          (unsigned int)f2bf(g0) | ((unsigned int)f2bf(g1) << 16);
    }
    float invden = 1.0f / (ws[WS_DEN + t] + 1e-5f);
    if (lo) {                                      // prefetch t+1
      int tn = (t + 1 < Tt) ? (t + 1) : t;
      size_t g = gbase + (size_t)tn * Dd;
      px = *(const float2*)(values + g);
      pm = *(const float2*)(masks + g);
      pd = *(const float2*)(deltas + g);
    }
    __syncthreads();                               // B2: staging + pbuf visible

    // ---- phase1: LSTM combine (lo); init gate accs; m-part gates (all); A (lo); E (w12-15) ----
    if (lo && t > 0) {
      #pragma unroll
      for (int r = 0; r < 4; r++) {
        float2 p = *(const float2*)(&pbuf[((r * 8 + cg) * 64 + lane) * 2]);
        float ig = sigmoidf_(aG0[r]);
        float fg = sigmoidf_(aG1[r]);
        c_reg[r] = fg * c_reg[r] + ig * p.x;
        h_reg[r] = p.y * tanhf_(c_reg[r]);
      }
    }
    aG0 = floatx4{biasG0, biasG0, biasG0, biasG0};
    aG1 = floatx4{biasG1, biasG1, biasG1, biasG1};
    {
      short8 mf0 = *(const short8*)(&act[l15 * 264 + 64 + quad * 8]);
      short8 mf1 = *(const short8*)(&act[l15 * 264 + 96 + quad * 8]);
      aG0 = __builtin_amdgcn_mfma_f32_16x16x32_bf16(mf0, wG[2],  aG0, 0, 0, 0);
      aG0 = __builtin_amdgcn_mfma_f32_16x16x32_bf16(mf1, wG[3],  aG0, 0, 0, 0);
      aG1 = __builtin_amdgcn_mfma_f32_16x16x32_bf16(mf0, wG[10], aG1, 0, 0, 0);
      aG1 = __builtin_amdgcn_mfma_f32_16x16x32_bf16(mf1, wG[11], aG1, 0, 0, 0);
      if (lo) {                                    // stage A: gamma_h decay, write h_dec
        short8 df0 = *(const short8*)(&dbuf[l15 * 72 + quad * 8]);
        short8 df1 = *(const short8*)(&dbuf[l15 * 72 + 32 + quad * 8]);
        floatx4 accA = floatx4{biasAC, biasAC, biasAC, biasAC};
        accA = __builtin_amdgcn_mfma_f32_16x16x32_bf16(df0, wX[0], accA, 0, 0, 0);
        accA = __builtin_amdgcn_mfma_f32_16x16x32_bf16(df1, wX[1], accA, 0, 0, 0);
        #pragma unroll
        for (int r = 0; r < 4; r++) {
          h_reg[r] *= __expf(-fmaxf(accA[r], 0.0f));
          act[(quad * 4 + r) * 264 + 128 + colh] = f2bf(h_reg[r]);
        }
      } else if (w >= 12) {                        // stage E matmul: alpha
        short8 gx0 = *(const short8*)(&gxbuf[l15 * 72 + quad * 8]);
        short8 gx1 = *(const short8*)(&gxbuf[l15 * 72 + 32 + quad * 8]);
        accP = floatx4{biasBE, biasBE, biasBE, biasBE};
        accP = __builtin_amdgcn_mfma_f32_16x16x32_bf16(gx0, wX[0], accP, 0, 0, 0);
        accP = __builtin_amdgcn_mfma_f32_16x16x32_bf16(gx1, wX[1], accP, 0, 0, 0);
        accP = __builtin_amdgcn_mfma_f32_16x16x32_bf16(mf0, wX[2], accP, 0, 0, 0);
        accP = __builtin_amdgcn_mfma_f32_16x16x32_bf16(mf1, wX[3], accP, 0, 0, 0);
      }
    }
    __syncthreads();                               // B3: h_dec visible

    // ---- phase2: h-part gates (all); stage B + epilogue (w8-11) ----
    {
      short8 hf0 = *(const short8*)(&act[l15 * 264 + 128 + quad * 8]);
      short8 hf1 = *(const short8*)(&act[l15 * 264 + 160 + quad * 8]);
      short8 hf2 = *(const short8*)(&act[l15 * 264 + 192 + quad * 8]);
      short8 hf3 = *(const short8*)(&act[l15 * 264 + 224 + quad * 8]);
      aG0 = __builtin_amdgcn_mfma_f32_16x16x32_bf16(hf0, wG[4],  aG0, 0, 0, 0);
      aG0 = __builtin_amdgcn_mfma_f32_16x16x32_bf16(hf1, wG[5],  aG0, 0, 0, 0);
      aG0 = __builtin_amdgcn_mfma_f32_16x16x32_bf16(hf2, wG[6],  aG0, 0, 0, 0);
      aG0 = __builtin_amdgcn_mfma_f32_16x16x32_bf16(hf3, wG[7],  aG0, 0, 0, 0);
      aG1 = __builtin_amdgcn_mfma_f32_16x16x32_bf16(hf0, wG[12], aG1, 0, 0, 0);
      aG1 = __builtin_amdgcn_mfma_f32_16x16x32_bf16(hf1, wG[13], aG1, 0, 0, 0);
      aG1 = __builtin_amdgcn_mfma_f32_16x16x32_bf16(hf2, wG[14], aG1, 0, 0, 0);
      aG1 = __builtin_amdgcn_mfma_f32_16x16x32_bf16(hf3, wG[15], aG1, 0, 0, 0);
      if (!lo && w < 12) {                         // stage B: x_h
        floatx4 accB = floatx4{biasBE, biasBE, biasBE, biasBE};
        accB = __builtin_amdgcn_mfma_f32_16x16x32_bf16(hf0, wX[0], accB, 0, 0, 0);
        accB = __builtin_amdgcn_mfma_f32_16x16x32_bf16(hf1, wX[1], accB, 0, 0, 0);
        accB = __builtin_amdgcn_mfma_f32_16x16x32_bf16(hf2, wX[2], accB, 0, 0, 0);
        accB = __builtin_amdgcn_mfma_f32_16x16x32_bf16(hf3, wX[3], accB, 0, 0, 0);
        #pragma unroll
        for (int r = 0; r < 4; r++) {
          int m = quad * 4 + r;
          float2 xm = *(const float2*)(&xmbuf[m * 132 + 2 * colD]);
          float xh = accB[r];
          loss_acc += fabsf(xm.x - xh) * xm.y * invden;          // loss1
          xhbuf[m * 68 + colD] = xh;
          xcbuf[m * 72 + colD] = f2bf(xm.y * xm.x + (1.0f - xm.y) * xh);
        }
      }
    }
    __syncthreads();                               // B4: x_c, x_h visible

    // ---- phase3 (w12-15): stage C (z_h) + loss2 + E epilogue + outputs ----
    if (w >= 12) {
      short8 xc0 = *(const short8*)(&xcbuf[l15 * 72 + quad * 8]);
      short8 xc1 = *(const short8*)(&xcbuf[l15 * 72 + 32 + quad * 8]);
      floatx4 accC = floatx4{biasAC, biasAC, biasAC, biasAC};
      accC = __builtin_amdgcn_mfma_f32_16x16x32_bf16(xc0, wX[4], accC, 0, 0, 0);
      accC = __builtin_amdgcn_mfma_f32_16x16x32_bf16(xc1, wX[5], accC, 0, 0, 0);
      #pragma unroll
      for (int r = 0; r < 4; r++) {
        int m = quad * 4 + r;
        float2 xm = *(const float2*)(&xmbuf[m * 132 + 2 * colD]);
        float zh = accC[r];
        float al = accP[r];
        float xh = xhbuf[m * 68 + colD];
        loss_acc += fabsf(xm.x - zh) * xm.y * invden;            // loss2
        float ch = al * zh + (1.0f - al) * xh;
        loss_acc += fabsf(xm.x - ch) * xm.y * invden;            // loss3
        float cc = xm.y * xm.x + (1.0f - xm.y) * ch;
        impt[r * (Tt * Dd)] = cc;
        act[m * 264 + colD] = f2bf(cc);
      }
      impt += Dd;
    }
    // (cc-part of this step's gates happens in phase0 of t+1; gates of t=47 are unused)
  }

  // ---- loss reduction ----
  float s = loss_acc;
  for (int off = 32; off > 0; off >>= 1) s += __shfl_down(s, off, 64);
  if (lane == 0) red[w] = s;
  __syncthreads();
  if (tid == 0) {
    float tot = 0.0f;
    #pragma unroll
    for (int i = 0; i < 16; i++) tot += red[i];
    atomicAdd(&ws[WS_LOSS], tot);
  }
}

// ---------------- kernel 3: finalize loss ----------------
__global__ void final_kernel(const float* __restrict__ ws, float* __restrict__ out) {
  if (threadIdx.x == 0 && blockIdx.x == 0) out[0] = 0.3f * ws[WS_LOSS];
}

extern "C" void kernel_launch(void* const* d_in, const int* in_sizes, int n_in,
                              void* d_out, int out_size, void* d_ws, size_t ws_size,
                              hipStream_t stream) {
  const float* values = (const float*)d_in[0];
  const float* masks  = (const float*)d_in[1];
  const float* deltas = (const float*)d_in[2];
  const float* W_td_h = (const float*)d_in[3];
  const float* b_td_h = (const float*)d_in[4];
  const float* W_td_x = (const float*)d_in[5];
  const float* b_td_x = (const float*)d_in[6];
  const float* W_hist = (const float*)d_in[7];
  const float* b_hist = (const float*)d_in[8];
  const float* W_feat = (const float*)d_in[9];
  const float* b_feat = (const float*)d_in[10];
  const float* W_comb = (const float*)d_in[11];
  const float* b_comb = (const float*)d_in[12];
  const float* W_ih   = (const float*)d_in[13];
  const float* W_hh   = (const float*)d_in[14];
  const float* b_ih   = (const float*)d_in[15];
  const float* b_hh   = (const float*)d_in[16];
  float* out = (float*)d_out;
  float* ws  = (float*)d_ws;   // uses 64 + 312*256 floats ≈ 320 KB

  prep_kernel<<<dim3(N_FRAGS), dim3(256), 0, stream>>>(W_td_h, W_hist, W_feat, W_comb,
                                                       W_ih, W_hh, ws);
  denom_kernel<<<dim3(48 * 16), dim3(256), 0, stream>>>(masks, ws);
  main_kernel<<<dim3(Bb / NB), dim3(NTHR), 0, stream>>>(values, masks, deltas, W_td_x,
                                                        b_td_h, b_td_x, b_hist, b_feat,
                                                        b_comb, b_ih, b_hh, ws, out);
  final_kernel<<<dim3(1), dim3(64), 0, stream>>>(ws, out);
}

// Round 5
// 361.603 us; speedup vs baseline: 1.6507x; 1.6507x over previous
//
#include <hip/hip_runtime.h>
#include <cmath>

// B,T,D,H = 4096,48,64,128
#define Bb 4096
#define Tt 48
#define Dd 64
#define Hh 128
#define NB 16      // batch rows per block (M of MFMA)
#define NTHR 512   // 8 waves

// Raw workgroup barrier WITHOUT the vmcnt(0) drain __syncthreads() implies.
// LDS visibility needs only lgkmcnt(0); global loads/stores in flight (input
// prefetch, imputation stores) must NOT be drained at phase boundaries.
#define BAR_LDS() asm volatile("s_waitcnt lgkmcnt(0)\n\ts_barrier" ::: "memory")

typedef unsigned short ushort_t;
typedef __attribute__((ext_vector_type(8))) short short8;    // 8 bf16 = 4 VGPRs (MFMA A/B frag)
typedef __attribute__((ext_vector_type(4))) float floatx4;   // MFMA C/D frag

// ---- workspace layout (floats) ----
#define WS_DEN   0     // denoms[48]
#define WS_LOSS  48
#define WS_FRAGS 64    // bf16 frag area starts here (16B aligned)
// frag indices (each frag = 64 lanes x 8 bf16 = 512 ushorts = 1 KB)
#define FR_F 0         // 256 frags: gates  [w:8][g:4][ks:8]   K=256 (c_c|m|h)
#define FR_A 256       // 16: W_td_h        [w:8][ks:2]        K=64
#define FR_B 272       // 16: W_hist        [w:4][ks:4]        K=128
#define FR_C 288       // 8 : W_feat masked [w:4][ks:2]        K=64
#define FR_E 296       // 16: W_comb        [w:4][ks:4]        K=128
#define N_FRAGS 312

__device__ __forceinline__ ushort_t f2bf(float x) {   // RNE float->bf16 bits
  unsigned int u = __float_as_uint(x);
  u += 0x7fffu + ((u >> 16) & 1u);
  return (ushort_t)(u >> 16);
}
__device__ __forceinline__ float sigmoidf_(float x) { return 1.0f / (1.0f + __expf(-x)); }
__device__ __forceinline__ float tanhf_(float x) { return 2.0f / (1.0f + __expf(-2.0f * x)) - 1.0f; }

// ---------------- kernel 0: pack weights into per-lane MFMA B-frags (bf16) ----------------
// B-frag layout for mfma_f32_16x16x32_bf16: lane l holds B[k=(l>>4)*8+j][n=l&15], j=0..7
__global__ void prep_kernel(const float* __restrict__ W_td_h, const float* __restrict__ W_hist,
                            const float* __restrict__ W_feat, const float* __restrict__ W_comb,
                            const float* __restrict__ W_ih, const float* __restrict__ W_hh,
                            float* __restrict__ ws) {
  int f = blockIdx.x;                 // one frag per block
  int tid = threadIdx.x;              // 256 threads, 2 elems each
  if (f == 0 && tid < 64) ws[tid] = 0.0f;   // zero denoms + loss
  ushort_t* fb = (ushort_t*)(ws + WS_FRAGS);
  #pragma unroll
  for (int u = 0; u < 2; u++) {
    int e = tid * 2 + u;              // 0..511 = l*8 + j
    int l = e >> 3, j = e & 7;
    int n16 = l & 15;
    int kq = ((l >> 4) << 3) + j;     // quad*8 + j  (0..31)
    float v;
    if (f < 256) {
      int w = f >> 5, g = (f >> 3) & 3, ks = f & 7;
      int n = g * 128 + w * 16 + n16;           // gate row in [512]
      int k = ks * 32 + kq;                     // 0..255: 0-127 -> W_ih, 128-255 -> W_hh
      v = (k < 128) ? W_ih[n * 128 + k] : W_hh[n * 128 + (k - 128)];
    } else if (f < 272) {
      int ff = f - 256, w = ff >> 1, ks = ff & 1;
      int n = w * 16 + n16;                     // 0..127
      v = W_td_h[n * 64 + ks * 32 + kq];
    } else if (f < 288) {
      int ff = f - 272, w = ff >> 2, ks = ff & 3;
      int n = w * 16 + n16;                     // 0..63
      v = W_hist[n * 128 + ks * 32 + kq];
    } else if (f < 296) {
      int ff = f - 288, w = ff >> 1, ks = ff & 1;
      int n = w * 16 + n16;
      int k = ks * 32 + kq;
      v = (n == k) ? 0.0f : W_feat[n * 64 + k];  // zeroed diagonal
    } else {
      int ff = f - 296, w = ff >> 2, ks = ff & 3;
      int n = w * 16 + n16;
      v = W_comb[n * 128 + ks * 32 + kq];       // cols: 0-63 gamma_x, 64-127 m
    }
    fb[f * 512 + e] = f2bf(v);
  }
}

// ---------------- kernel 1: denom_t = sum over [B,D] of masks[:,t,:] ----------------
__global__ void denom_kernel(const float* __restrict__ masks, float* __restrict__ ws) {
  int t = blockIdx.x >> 4;
  int chunk = blockIdx.x & 15;
  int base = chunk * 256;
  int tid = threadIdx.x;
  int j = tid & 63;
  int brow = tid >> 6;
  float s = 0.0f;
  for (int i = 0; i < 64; i++) {
    int b = base + i * 4 + brow;
    s += masks[((size_t)b * Tt + t) * Dd + j];
  }
  for (int off = 32; off > 0; off >>= 1) s += __shfl_down(s, off, 64);
  __shared__ float red[4];
  if ((tid & 63) == 0) red[tid >> 6] = s;
  __syncthreads();
  if (tid == 0) atomicAdd(&ws[WS_DEN + t], red[0] + red[1] + red[2] + red[3]);
}

// ---------------- kernel 2: persistent MFMA recurrence ----------------
__global__ __launch_bounds__(NTHR, 2)
void main_kernel(const float* __restrict__ values, const float* __restrict__ masks,
                 const float* __restrict__ deltas, const float* __restrict__ W_td_x,
                 const float* __restrict__ b_td_h, const float* __restrict__ b_td_x,
                 const float* __restrict__ b_hist, const float* __restrict__ b_feat,
                 const float* __restrict__ b_comb,
                 const float* __restrict__ b_ih, const float* __restrict__ b_hh,
                 float* ws, float* __restrict__ out) {
  // LDS (~28 KB)
  __shared__ __align__(16) ushort_t act[16 * 264];   // bf16 [16][256+8]: c_c | m | h_dec
  __shared__ __align__(16) ushort_t dbuf[16 * 72];   // bf16 d
  __shared__ __align__(16) ushort_t gxbuf[16 * 72];  // bf16 gamma_x
  __shared__ __align__(16) ushort_t xcbuf[16 * 72];  // bf16 x_c
  __shared__ __align__(16) float xmbuf[16 * 132];    // fp32 interleaved [x,m] pairs
  __shared__ __align__(16) float xhbuf[16 * 68];     // fp32 x_h
  __shared__ float sden[48];                         // 1/(denom_t + 1e-5), loaded once
  __shared__ float red[8];

  int tid = threadIdx.x;
  int w = tid >> 6;            // wave 0..7
  int lane = tid & 63;
  int l15 = lane & 15;
  int quad = lane >> 4;
  int b0 = blockIdx.x * NB;
  const ushort_t* fb = (const ushort_t*)(ws + WS_FRAGS);

  // ---- one-time: denom table to LDS ----
  for (int i = tid; i < 48; i += NTHR) sden[i] = 1.0f / (ws[WS_DEN + i] + 1e-5f);

  // ---- one-time: all weights into registers (per-wave-private frags) ----
  short8 wF[32];
  #pragma unroll
  for (int g = 0; g < 4; g++)
    #pragma unroll
    for (int ks = 0; ks < 8; ks++)
      wF[g * 8 + ks] = *(const short8*)(fb + (size_t)(FR_F + w * 32 + g * 8 + ks) * 512 + lane * 8);
  short8 wA[2];
  #pragma unroll
  for (int ks = 0; ks < 2; ks++)
    wA[ks] = *(const short8*)(fb + (size_t)(FR_A + w * 2 + ks) * 512 + lane * 8);
  short8 wBE[4];
  short8 wC[2];
  if (w < 4) {
    #pragma unroll
    for (int ks = 0; ks < 4; ks++)
      wBE[ks] = *(const short8*)(fb + (size_t)(FR_B + w * 4 + ks) * 512 + lane * 8);
  } else {
    #pragma unroll
    for (int ks = 0; ks < 4; ks++)
      wBE[ks] = *(const short8*)(fb + (size_t)(FR_E + (w - 4) * 4 + ks) * 512 + lane * 8);
    #pragma unroll
    for (int ks = 0; ks < 2; ks++)
      wC[ks] = *(const short8*)(fb + (size_t)(FR_C + (w - 4) * 2 + ks) * 512 + lane * 8);
  }

  // ---- biases at this lane's owned columns ----
  int colh = w * 16 + l15;           // 0..127 (A cols, F gate cols)
  float biasF0 = b_ih[colh]       + b_hh[colh];
  float biasF1 = b_ih[128 + colh] + b_hh[128 + colh];
  float biasF2 = b_ih[256 + colh] + b_hh[256 + colh];
  float biasF3 = b_ih[384 + colh] + b_hh[384 + colh];
  float biasA  = b_td_h[colh];
  int colD = (w & 3) * 16 + l15;     // 0..63 (B/C/E cols)
  float biasBE = (w < 4) ? b_hist[colD] : b_comb[colD];
  float biasC  = b_feat[colD];       // used by waves 4-7

  // ---- input-load mapping (2 consecutive elements per thread) ----
  int e0 = tid * 2;
  int lb = e0 >> 6, li = e0 & 63;            // li is even
  size_t gbase = ((size_t)(b0 + lb) * Tt) * Dd + li;
  float diag0 = W_td_x[li * 64 + li], diag1 = W_td_x[(li + 1) * 64 + (li + 1)];
  float btx0 = b_td_x[li], btx1 = b_td_x[li + 1];

  // ---- hoisted addresses ----
  int ha[4];                                  // act h-col write addrs (ushort idx)
  float* impp[4];                             // imputation store pointers (advance 64/step)
  #pragma unroll
  for (int r = 0; r < 4; r++) {
    int m = quad * 4 + r;
    ha[r] = m * 264 + 128 + colh;
    impp[r] = out + 1 + (size_t)(b0 + m) * Tt * Dd + colD;
  }

  float h_reg[4] = {0.f, 0.f, 0.f, 0.f};
  float c_reg[4] = {0.f, 0.f, 0.f, 0.f};
  float loss_acc = 0.0f;

  // ---- prefetch t=0 inputs ----
  float2 px = *(const float2*)(values + gbase);
  float2 pm = *(const float2*)(masks + gbase);
  float2 pd = *(const float2*)(deltas + gbase);

  __syncthreads();                            // full sync once: sden visible

  for (int t = 0; t < Tt; t++) {
    BAR_LDS();                                // B1: prev step's act/xmbuf reads done
    // ---- stage prefetched inputs to LDS; gamma_x elementwise ----
    *(float4*)(&xmbuf[lb * 132 + 2 * li]) = make_float4(px.x, pm.x, px.y, pm.y);
    *(unsigned int*)(&act[lb * 264 + 64 + li]) =
        (unsigned int)f2bf(pm.x) | ((unsigned int)f2bf(pm.y) << 16);
    *(unsigned int*)(&dbuf[lb * 72 + li]) =
        (unsigned int)f2bf(pd.x) | ((unsigned int)f2bf(pd.y) << 16);
    float g0 = __expf(-fmaxf(pd.x * diag0 + btx0, 0.0f));
    float g1 = __expf(-fmaxf(pd.y * diag1 + btx1, 0.0f));
    *(unsigned int*)(&gxbuf[lb * 72 + li]) =
        (unsigned int)f2bf(g0) | ((unsigned int)f2bf(g1) << 16);
    float invden = sden[t];
    // ---- init F gate accumulators (persist across slots) ----
    floatx4 a0 = {biasF0, biasF0, biasF0, biasF0};
    floatx4 a1 = {biasF1, biasF1, biasF1, biasF1};
    floatx4 a2 = {biasF2, biasF2, biasF2, biasF2};
    floatx4 a3 = {biasF3, biasF3, biasF3, biasF3};
    // ---- prefetch t+1 inputs (latency now genuinely spans the step) ----
    {
      int tn = (t + 1 < Tt) ? (t + 1) : t;
      size_t g = gbase + (size_t)tn * Dd;
      px = *(const float2*)(values + g);
      pm = *(const float2*)(masks + g);
      pd = *(const float2*)(deltas + g);
    }
    BAR_LDS();                                // B2: staging visible

    // ---- S1: A (gamma_h) + F m-part (K=64..127). Keep m-frags for E. ----
    short8 mf0 = *(const short8*)(&act[l15 * 264 + 64 + quad * 8]);
    short8 mf1 = *(const short8*)(&act[l15 * 264 + 96 + quad * 8]);
    {
      short8 df0 = *(const short8*)(&dbuf[l15 * 72 + quad * 8]);
      short8 df1 = *(const short8*)(&dbuf[l15 * 72 + 32 + quad * 8]);
      floatx4 accA = {biasA, biasA, biasA, biasA};
      accA = __builtin_amdgcn_mfma_f32_16x16x32_bf16(df0, wA[0], accA, 0, 0, 0);
      accA = __builtin_amdgcn_mfma_f32_16x16x32_bf16(df1, wA[1], accA, 0, 0, 0);
      a0 = __builtin_amdgcn_mfma_f32_16x16x32_bf16(mf0, wF[2],  a0, 0, 0, 0);
      a0 = __builtin_amdgcn_mfma_f32_16x16x32_bf16(mf1, wF[3],  a0, 0, 0, 0);
      a1 = __builtin_amdgcn_mfma_f32_16x16x32_bf16(mf0, wF[10], a1, 0, 0, 0);
      a1 = __builtin_amdgcn_mfma_f32_16x16x32_bf16(mf1, wF[11], a1, 0, 0, 0);
      a2 = __builtin_amdgcn_mfma_f32_16x16x32_bf16(mf0, wF[18], a2, 0, 0, 0);
      a2 = __builtin_amdgcn_mfma_f32_16x16x32_bf16(mf1, wF[19], a2, 0, 0, 0);
      a3 = __builtin_amdgcn_mfma_f32_16x16x32_bf16(mf0, wF[26], a3, 0, 0, 0);
      a3 = __builtin_amdgcn_mfma_f32_16x16x32_bf16(mf1, wF[27], a3, 0, 0, 0);
      #pragma unroll
      for (int r = 0; r < 4; r++) {
        h_reg[r] *= __expf(-fmaxf(accA[r], 0.0f));
        act[ha[r]] = f2bf(h_reg[r]);
      }
    }
    BAR_LDS();                                // B3: h_dec staged

    // ---- S2: B (w0-3) / E-mat (w4-7) + F h-part (all). ----
    floatx4 accP = {biasBE, biasBE, biasBE, biasBE};
    {
      short8 hf0 = *(const short8*)(&act[l15 * 264 + 128 + quad * 8]);
      short8 hf1 = *(const short8*)(&act[l15 * 264 + 160 + quad * 8]);
      short8 hf2 = *(const short8*)(&act[l15 * 264 + 192 + quad * 8]);
      short8 hf3 = *(const short8*)(&act[l15 * 264 + 224 + quad * 8]);
      if (w < 4) {
        accP = __builtin_amdgcn_mfma_f32_16x16x32_bf16(hf0, wBE[0], accP, 0, 0, 0);
        accP = __builtin_amdgcn_mfma_f32_16x16x32_bf16(hf1, wBE[1], accP, 0, 0, 0);
        accP = __builtin_amdgcn_mfma_f32_16x16x32_bf16(hf2, wBE[2], accP, 0, 0, 0);
        accP = __builtin_amdgcn_mfma_f32_16x16x32_bf16(hf3, wBE[3], accP, 0, 0, 0);
      } else {
        short8 gx0 = *(const short8*)(&gxbuf[l15 * 72 + quad * 8]);
        short8 gx1 = *(const short8*)(&gxbuf[l15 * 72 + 32 + quad * 8]);
        accP = __builtin_amdgcn_mfma_f32_16x16x32_bf16(gx0, wBE[0], accP, 0, 0, 0);
        accP = __builtin_amdgcn_mfma_f32_16x16x32_bf16(gx1, wBE[1], accP, 0, 0, 0);
        accP = __builtin_amdgcn_mfma_f32_16x16x32_bf16(mf0, wBE[2], accP, 0, 0, 0);
        accP = __builtin_amdgcn_mfma_f32_16x16x32_bf16(mf1, wBE[3], accP, 0, 0, 0);
      }
      a0 = __builtin_amdgcn_mfma_f32_16x16x32_bf16(hf0, wF[4],  a0, 0, 0, 0);
      a0 = __builtin_amdgcn_mfma_f32_16x16x32_bf16(hf1, wF[5],  a0, 0, 0, 0);
      a0 = __builtin_amdgcn_mfma_f32_16x16x32_bf16(hf2, wF[6],  a0, 0, 0, 0);
      a0 = __builtin_amdgcn_mfma_f32_16x16x32_bf16(hf3, wF[7],  a0, 0, 0, 0);
      a1 = __builtin_amdgcn_mfma_f32_16x16x32_bf16(hf0, wF[12], a1, 0, 0, 0);
      a1 = __builtin_amdgcn_mfma_f32_16x16x32_bf16(hf1, wF[13], a1, 0, 0, 0);
      a1 = __builtin_amdgcn_mfma_f32_16x16x32_bf16(hf2, wF[14], a1, 0, 0, 0);
      a1 = __builtin_amdgcn_mfma_f32_16x16x32_bf16(hf3, wF[15], a1, 0, 0, 0);
      a2 = __builtin_amdgcn_mfma_f32_16x16x32_bf16(hf0, wF[20], a2, 0, 0, 0);
      a2 = __builtin_amdgcn_mfma_f32_16x16x32_bf16(hf1, wF[21], a2, 0, 0, 0);
      a2 = __builtin_amdgcn_mfma_f32_16x16x32_bf16(hf2, wF[22], a2, 0, 0, 0);
      a2 = __builtin_amdgcn_mfma_f32_16x16x32_bf16(hf3, wF[23], a2, 0, 0, 0);
      a3 = __builtin_amdgcn_mfma_f32_16x16x32_bf16(hf0, wF[28], a3, 0, 0, 0);
      a3 = __builtin_amdgcn_mfma_f32_16x16x32_bf16(hf1, wF[29], a3, 0, 0, 0);
      a3 = __builtin_amdgcn_mfma_f32_16x16x32_bf16(hf2, wF[30], a3, 0, 0, 0);
      a3 = __builtin_amdgcn_mfma_f32_16x16x32_bf16(hf3, wF[31], a3, 0, 0, 0);
      if (w < 4) {                            // B epilogue: loss1, x_h, x_c
        #pragma unroll
        for (int r = 0; r < 4; r++) {
          int m = quad * 4 + r;
          float2 xm = *(const float2*)(&xmbuf[m * 132 + 2 * colD]);
          float xh = accP[r];
          loss_acc += fabsf(xm.x - xh) * xm.y * invden;
          xhbuf[m * 68 + colD] = xh;
          xcbuf[m * 72 + colD] = f2bf(xm.y * xm.x + (1.0f - xm.y) * xh);
        }
      }
    }
    BAR_LDS();                                // B4: x_c, x_h staged

    // ---- S3 (w4-7): C (z_h) + E epilogue, all register-local ----
    if (w >= 4) {
      short8 xc0 = *(const short8*)(&xcbuf[l15 * 72 + quad * 8]);
      short8 xc1 = *(const short8*)(&xcbuf[l15 * 72 + 32 + quad * 8]);
      floatx4 accC = {biasC, biasC, biasC, biasC};
      accC = __builtin_amdgcn_mfma_f32_16x16x32_bf16(xc0, wC[0], accC, 0, 0, 0);
      accC = __builtin_amdgcn_mfma_f32_16x16x32_bf16(xc1, wC[1], accC, 0, 0, 0);
      #pragma unroll
      for (int r = 0; r < 4; r++) {
        int m = quad * 4 + r;
        float2 xm = *(const float2*)(&xmbuf[m * 132 + 2 * colD]);
        float xh = xhbuf[m * 68 + colD];
        float zh = accC[r];
        float al = accP[r];
        loss_acc += fabsf(xm.x - zh) * xm.y * invden;        // loss2
        float ch = al * zh + (1.0f - al) * xh;
        loss_acc += fabsf(xm.x - ch) * xm.y * invden;        // loss3
        float cc = xm.y * xm.x + (1.0f - xm.y) * ch;
        *impp[r] = cc;                                       // store never drained in-loop
        impp[r] += Dd;
        act[m * 264 + colD] = f2bf(cc);
      }
    } else {
      #pragma unroll
      for (int r = 0; r < 4; r++) impp[r] += Dd;   // keep pointers uniform (unused by w<4)
    }
    BAR_LDS();                                // B5: c_c staged

    // ---- S5: F c_c-part (K=0..63) + LSTM update ----
    {
      short8 cf0 = *(const short8*)(&act[l15 * 264 + quad * 8]);
      short8 cf1 = *(const short8*)(&act[l15 * 264 + 32 + quad * 8]);
      a0 = __builtin_amdgcn_mfma_f32_16x16x32_bf16(cf0, wF[0],  a0, 0, 0, 0);
      a0 = __builtin_amdgcn_mfma_f32_16x16x32_bf16(cf1, wF[1],  a0, 0, 0, 0);
      a1 = __builtin_amdgcn_mfma_f32_16x16x32_bf16(cf0, wF[8],  a1, 0, 0, 0);
      a1 = __builtin_amdgcn_mfma_f32_16x16x32_bf16(cf1, wF[9],  a1, 0, 0, 0);
      a2 = __builtin_amdgcn_mfma_f32_16x16x32_bf16(cf0, wF[16], a2, 0, 0, 0);
      a2 = __builtin_amdgcn_mfma_f32_16x16x32_bf16(cf1, wF[17], a2, 0, 0, 0);
      a3 = __builtin_amdgcn_mfma_f32_16x16x32_bf16(cf0, wF[24], a3, 0, 0, 0);
      a3 = __builtin_amdgcn_mfma_f32_16x16x32_bf16(cf1, wF[25], a3, 0, 0, 0);
      #pragma unroll
      for (int r = 0; r < 4; r++) {
        float ig = sigmoidf_(a0[r]);
        float fg = sigmoidf_(a1[r]);
        float gg = tanhf_(a2[r]);
        float og = sigmoidf_(a3[r]);
        c_reg[r] = fg * c_reg[r] + ig * gg;
        h_reg[r] = og * tanhf_(c_reg[r]);
      }
    }
  }

  // ---- loss reduction ----
  float s = loss_acc;
  for (int off = 32; off > 0; off >>= 1) s += __shfl_down(s, off, 64);
  if (lane == 0) red[w] = s;
  __syncthreads();
  if (tid == 0) {
    float tot = 0.0f;
    #pragma unroll
    for (int i = 0; i < 8; i++) tot += red[i];
    atomicAdd(&ws[WS_LOSS], tot);
  }
}

// ---------------- kernel 3: finalize loss ----------------
__global__ void final_kernel(const float* __restrict__ ws, float* __restrict__ out) {
  if (threadIdx.x == 0 && blockIdx.x == 0) out[0] = 0.3f * ws[WS_LOSS];
}

extern "C" void kernel_launch(void* const* d_in, const int* in_sizes, int n_in,
                              void* d_out, int out_size, void* d_ws, size_t ws_size,
                              hipStream_t stream) {
  const float* values = (const float*)d_in[0];
  const float* masks  = (const float*)d_in[1];
  const float* deltas = (const float*)d_in[2];
  const float* W_td_h = (const float*)d_in[3];
  const float* b_td_h = (const float*)d_in[4];
  const float* W_td_x = (const float*)d_in[5];
  const float* b_td_x = (const float*)d_in[6];
  const float* W_hist = (const float*)d_in[7];
  const float* b_hist = (const float*)d_in[8];
  const float* W_feat = (const float*)d_in[9];
  const float* b_feat = (const float*)d_in[10];
  const float* W_comb = (const float*)d_in[11];
  const float* b_comb = (const float*)d_in[12];
  const float* W_ih   = (const float*)d_in[13];
  const float* W_hh   = (const float*)d_in[14];
  const float* b_ih   = (const float*)d_in[15];
  const float* b_hh   = (const float*)d_in[16];
  float* out = (float*)d_out;
  float* ws  = (float*)d_ws;   // uses 64 + 312*256 floats ≈ 320 KB

  prep_kernel<<<dim3(N_FRAGS), dim3(256), 0, stream>>>(W_td_h, W_hist, W_feat, W_comb,
                                                       W_ih, W_hh, ws);
  denom_kernel<<<dim3(48 * 16), dim3(256), 0, stream>>>(masks, ws);
  main_kernel<<<dim3(Bb / NB), dim3(NTHR), 0, stream>>>(values, masks, deltas, W_td_x,
                                                        b_td_h, b_td_x, b_hist, b_feat,
                                                        b_comb, b_ih, b_hh, ws, out);
  final_kernel<<<dim3(1), dim3(64), 0, stream>>>(ws, out);
}